// Round 17
// baseline (164.015 us; speedup 1.0000x reference)
//
#include <hip/hip_runtime.h>

// VQ codebook: z_e [32,64,64,64] f32 (B,C,W,H), emb [1024,64] f32.
// Outputs: quantized [32,64,64,64] f32, indices [131072] (as f32), vq_loss [1].
//
// R17: scan moves to mfma_f32_32x32x16_bf16 (32 codes x 32 points per wave-
// tile). Rationale: 7 variants pinned at ~70us with VALU busy-time constant
// ~40us -> VALU-instruction-bound at ~23 instrs/score. 32x32 halves per-score
// epilogue+overhead and runs MFMA at the 2495 TF ceiling. A/B k-mapping
// self-cancels; D read via the VERIFIED 32x32 C/D map; ties always flag
// (gap 0 <= DELTA) -> exact rescue; so indices remain exact-argmin.
// e staged via R16's dbuf global_load_lds (8KB/tile). Everything else R12.

#define CDIM   64
#define KCODES 1024
#define NPTS   131072
#define WH     4096
#define CWH    262144
#define DELTA  0.02f

typedef __attribute__((ext_vector_type(4)))  float f32x4;
typedef __attribute__((ext_vector_type(16))) float f32x16;
typedef __attribute__((ext_vector_type(8)))  short bf16x8;
typedef __attribute__((ext_vector_type(8)))  unsigned short u16x8;

__device__ inline unsigned short f2bf(float f) {
    unsigned u = __float_as_uint(f);
    return (unsigned short)((u + 0x7FFFu + ((u >> 16) & 1u)) >> 16);
}
__device__ inline float bf2f(unsigned short h) {
    return __uint_as_float(((unsigned)h) << 16);
}

// ---------- prep: E (exact R1 order) + 32x32 A-frag swizzle + cnt=0 ----------
// A-frag (M=32,K=16) lane map: row=lane&31, k=(lane>>5)*8+j (k-permutation
// cancels against B built with the same map). Chunk (ct, split, q) = 512 us.
__global__ __launch_bounds__(256) void vq_prep(const float* __restrict__ emb,
                                               unsigned short* __restrict__ e_swz,
                                               float* __restrict__ E,
                                               int* __restrict__ cnt) {
    const int id = blockIdx.x * 256 + threadIdx.x;
    if (id == 0) cnt[0] = 0;

    if (id < KCODES) {   // E[c], bit-identical to R1
        const int c = id;
        const float4* e4 = (const float4*)(emb + c * CDIM);
        float s = 0.f;
#pragma unroll
        for (int i = 0; i < CDIM / 4; ++i) {
            float4 v = e4[i];
            s = fmaf(v.x, v.x, s); s = fmaf(v.y, v.y, s);
            s = fmaf(v.z, v.z, s); s = fmaf(v.w, v.w, s);
        }
        E[c] = s;
    }

    if (id < KCODES * 8) {
        const int c  = id >> 3;        // code
        const int q  = (id >> 1) & 3;  // K=16 slice (k = q*16 + h*8 + j)
        const int h  = id & 1;         // lane>>5 half
        const int ct = c >> 5, col = c & 31;
        const size_t off = (size_t)((h << 5) | col) * 8;
        const size_t bh  = (size_t)(ct * 8 + q) * 512 + off;       // hi chunks 0..3
        const size_t bl  = (size_t)(ct * 8 + 4 + q) * 512 + off;   // lo chunks 4..7
        u16x8 his, los;
#pragma unroll
        for (int j = 0; j < 8; ++j) {
            float v = emb[c * CDIM + q * 16 + h * 8 + j];
            unsigned short hi = f2bf(v);
            unsigned short lo = f2bf(v - bf2f(hi));
            his[j] = hi;
            los[j] = lo;
        }
        *(u16x8*)&e_swz[bh] = his;
        *(u16x8*)&e_swz[bl] = los;
    }
}

// ---------- MFMA scan: 256 thr / 4 waves, one 32-point tile per wave ----------
__global__ __launch_bounds__(256) void vq_scan_mfma(const float* __restrict__ z_e,
                                                    const unsigned short* __restrict__ e_swz,
                                                    const float* __restrict__ E,
                                                    int* __restrict__ bestk,
                                                    int* __restrict__ flagA) {
    const int tid = threadIdx.x;
    const int n0  = blockIdx.x * 128;
    const int b   = n0 >> 12;
    const int wh0 = n0 & 4095;

    __shared__ unsigned short zfrag[4][2][4][512];   // 32 KB: [pt32][split][q]
    __shared__ unsigned short se[2][4096];           // 16 KB: 8KB e-tile dbuf

    const int lane = tid & 63;
    const int w    = tid >> 6;    // 0..3: wave -> 32-point tile

    // stage e-tile 0 (8KB = 2 DMA sweeps of 4KB)
    {
        const unsigned short* g0 = e_swz + (size_t)w * 512 + (size_t)lane * 8;
        const unsigned short* g1 = g0 + 2048;
        auto* d0 = (__attribute__((address_space(3))) void*)&se[0][w * 512];
        auto* d1 = (__attribute__((address_space(3))) void*)&se[0][2048 + w * 512];
        __builtin_amdgcn_global_load_lds((const __attribute__((address_space(1))) void*)g0, d0, 16, 0, 0);
        __builtin_amdgcn_global_load_lds((const __attribute__((address_space(1))) void*)g1, d1, 16, 0, 0);
    }

    // z staging. B-frag (K=16,N=32) lane map: col=lane&31, k=(lane>>5)*8+j.
    const float* zp = z_e + (size_t)b * CWH + wh0;
#pragma unroll 4
    for (int i = 0; i < 32; ++i) {
        int flat = i * 256 + tid;
        int c = flat >> 7, p = flat & 127;
        float v = zp[(size_t)c * WH + p];
        unsigned short hi = f2bf(v);
        unsigned short lo = f2bf(v - bf2f(hi));
        int q = c >> 4, h = (c >> 3) & 1, j = c & 7;
        int slot = ((h << 5) | (p & 31)) * 8 + j;
        zfrag[p >> 5][0][q][slot] = hi;
        zfrag[p >> 5][1][q][slot] = lo;
    }
    __syncthreads();   // zfrag + tile-0 DMA drained

    bf16x8 zh[4], zl[4];
#pragma unroll
    for (int q = 0; q < 4; ++q) {
        zh[q] = *(const bf16x8*)&zfrag[w][0][q][lane * 8];
        zl[q] = *(const bf16x8*)&zfrag[w][1][q][lane * 8];
    }

    const int h4 = ((lane >> 5) << 2);

    float m1a = 1e30f, m2a = 1e30f; int k1a = 0;

    for (int ct = 0; ct < KCODES / 32; ++ct) {
        // stage tile ct+1 into the other buffer (wraps on last iter)
        {
            const int ctn = (ct + 1) & 31;
            const unsigned short* g0 =
                e_swz + (size_t)ctn * 4096 + (size_t)w * 512 + (size_t)lane * 8;
            const unsigned short* g1 = g0 + 2048;
            auto* d0 = (__attribute__((address_space(3))) void*)&se[(ct + 1) & 1][w * 512];
            auto* d1 = (__attribute__((address_space(3))) void*)&se[(ct + 1) & 1][2048 + w * 512];
            __builtin_amdgcn_global_load_lds((const __attribute__((address_space(1))) void*)g0, d0, 16, 0, 0);
            __builtin_amdgcn_global_load_lds((const __attribute__((address_space(1))) void*)g1, d1, 16, 0, 0);
        }

        const unsigned short* cur = se[ct & 1];
        bf16x8 eh[4], el[4];
#pragma unroll
        for (int q = 0; q < 4; ++q) {
            eh[q] = *(const bf16x8*)&cur[q * 512 + lane * 8];
            el[q] = *(const bf16x8*)&cur[(4 + q) * 512 + lane * 8];
        }

        f32x16 acc = {0.f,0.f,0.f,0.f,0.f,0.f,0.f,0.f,
                      0.f,0.f,0.f,0.f,0.f,0.f,0.f,0.f};
#pragma unroll
        for (int q = 0; q < 4; ++q)
            acc = __builtin_amdgcn_mfma_f32_32x32x16_bf16(eh[q], zh[q], acc, 0, 0, 0);
#pragma unroll
        for (int q = 0; q < 4; ++q)
            acc = __builtin_amdgcn_mfma_f32_32x32x16_bf16(eh[q], zl[q], acc, 0, 0, 0);
#pragma unroll
        for (int q = 0; q < 4; ++q)
            acc = __builtin_amdgcn_mfma_f32_32x32x16_bf16(el[q], zh[q], acc, 0, 0, 0);

        // D map (verified): col=lane&31, row=(reg&3)+8*(reg>>2)+4*(lane>>5)
#pragma unroll
        for (int r2 = 0; r2 < 4; ++r2) {
            const f32x4 Ev = *(const f32x4*)(E + ct * 32 + r2 * 8 + h4);
            const int kb = ct * 32 + r2 * 8 + h4;
#pragma unroll
            for (int i = 0; i < 4; ++i) {
                float s0 = fmaf(-2.0f, acc[r2 * 4 + i], Ev[i]);
                if (s0 < m1a) { m2a = m1a; m1a = s0; k1a = kb + i; } else m2a = fminf(m2a, s0);
            }
        }
        __syncthreads();   // tile ct+1 staged + all waves done with cur
    }

    // lanes l and l^32 hold the same point column: single merge step
    {
        float om1 = __shfl_xor(m1a, 32); int ok1 = __shfl_xor(k1a, 32); float om2 = __shfl_xor(m2a, 32);
        bool take = (om1 < m1a) || (om1 == m1a && ok1 < k1a);
        float nm2 = take ? fminf(m1a, om2) : fminf(m2a, om1);
        if (take) { m1a = om1; k1a = ok1; }
        m2a = nm2;
    }

    if (lane < 32) {
        int na = n0 + w * 32 + lane;
        bestk[na] = k1a;
        flagA[na] = (m2a - m1a <= DELTA) ? 1 : 0;
    }
}

// ---------- rescue plumbing (R12 verbatim) ----------
__global__ __launch_bounds__(256) void vq_compact(const int* __restrict__ flagA,
                                                  int* __restrict__ list,
                                                  int* __restrict__ cnt) {
    int n = blockIdx.x * 256 + threadIdx.x;
    if (n < NPTS && flagA[n]) { int p = atomicAdd(cnt, 1); list[p] = n; }
}

__global__ __launch_bounds__(256) void vq_rescue(const float* __restrict__ z_e,
                                                 const float* __restrict__ emb,
                                                 const float* __restrict__ E,
                                                 const int* __restrict__ list,
                                                 const int* __restrict__ cnt,
                                                 int* __restrict__ bestk) {
    const int total  = cnt[0];
    const int lane   = threadIdx.x & 63;
    const int wid    = (blockIdx.x * 256 + threadIdx.x) >> 6;
    const int nwaves = (gridDim.x * 256) >> 6;

    for (int i = wid; i < total; i += nwaves) {
        const int n  = list[i];
        const int b  = n >> 12, wh = n & 4095;
        const float* zp = z_e + (size_t)b * CWH + wh;
        float z[CDIM];
#pragma unroll
        for (int c = 0; c < CDIM; ++c) z[c] = zp[c * WH];

        float best = 1e30f; int bk = 0;
        const int kbase = lane * 16;
#pragma unroll 4
        for (int j = 0; j < 16; ++j) {
            const int k = kbase + j;
            const float4* er4 = (const float4*)(emb + k * CDIM);
            float d0 = 0.f, d1 = 0.f, d2 = 0.f, d3 = 0.f;
#pragma unroll
            for (int c4 = 0; c4 < CDIM / 4; ++c4) {
                float4 v = er4[c4];
                d0 = fmaf(z[4 * c4 + 0], v.x, d0);
                d1 = fmaf(z[4 * c4 + 1], v.y, d1);
                d2 = fmaf(z[4 * c4 + 2], v.z, d2);
                d3 = fmaf(z[4 * c4 + 3], v.w, d3);
            }
            float dot   = (d0 + d1) + (d2 + d3);
            float score = fmaf(-2.0f, dot, E[k]);
            if (score < best) { best = score; bk = k; }
        }
#pragma unroll
        for (int d = 1; d < 64; d <<= 1) {
            float ob = __shfl_xor(best, d);
            int   ok = __shfl_xor(bk, d);
            if (ob < best || (ob == best && ok < bk)) { best = ob; bk = ok; }
        }
        if (lane == 0) bestk[n] = bk;
    }
}

// ---------- merge: 4 consecutive points x 8 channels per thread (R12 verbatim) ----------
__global__ __launch_bounds__(256) void vq_merge(const float* __restrict__ z_e,
                                                const float* __restrict__ emb,
                                                const int* __restrict__ kf,
                                                float* __restrict__ out_q,
                                                float* __restrict__ out_idx,
                                                float* __restrict__ partials) {
    const int tid = threadIdx.x;
    const int cq  = tid >> 5;
    const int pq  = tid & 31;
    const int n0  = blockIdx.x * 128 + pq * 4;
    const int b   = n0 >> 12;
    const int wh  = n0 & 4095;

    const int4 mk4 = *(const int4*)&kf[n0];
    if (cq == 0) {
        float4 fx = { (float)mk4.x, (float)mk4.y, (float)mk4.z, (float)mk4.w };
        *(float4*)&out_idx[n0] = fx;
    }

    const float* zb = z_e   + (size_t)b * CWH + wh;
    float*       qb = out_q + (size_t)b * CWH + wh;
    const int c0 = cq * 8;
    float lsum = 0.f;
#pragma unroll
    for (int cc = 0; cc < 8; ++cc) {
        const int c = c0 + cc;
        float4 z4 = *(const float4*)&zb[(size_t)c * WH];
        float4 q4;
        q4.x = emb[mk4.x * CDIM + c];
        q4.y = emb[mk4.y * CDIM + c];
        q4.z = emb[mk4.z * CDIM + c];
        q4.w = emb[mk4.w * CDIM + c];
        *(float4*)&qb[(size_t)c * WH] = q4;
        float dx = q4.x - z4.x, dy = q4.y - z4.y;
        float dz = q4.z - z4.z, dw = q4.w - z4.w;
        lsum = fmaf(dx, dx, lsum); lsum = fmaf(dy, dy, lsum);
        lsum = fmaf(dz, dz, lsum); lsum = fmaf(dw, dw, lsum);
    }

    __shared__ float red[256];
    red[tid] = lsum;
    __syncthreads();
    for (int s = 128; s > 0; s >>= 1) {
        if (tid < s) red[tid] += red[tid + s];
        __syncthreads();
    }
    if (tid == 0) partials[blockIdx.x] = red[0];
}

__global__ __launch_bounds__(1024) void vq_loss_fin(const float* __restrict__ partials,
                                                    float* __restrict__ loss) {
    __shared__ float red[1024];
    int t = threadIdx.x;
    red[t] = partials[t];
    __syncthreads();
    for (int s = 512; s > 0; s >>= 1) {
        if (t < s) red[t] += red[t + s];
        __syncthreads();
    }
    if (t == 0) loss[0] = red[0] * (1.25f / 8388608.0f);
}

extern "C" void kernel_launch(void* const* d_in, const int* in_sizes, int n_in,
                              void* d_out, int out_size, void* d_ws, size_t ws_size,
                              hipStream_t stream) {
    const float* z_e = (const float*)d_in[0];
    const float* emb = (const float*)d_in[1];

    float* out      = (float*)d_out;
    float* out_q    = out;
    float* out_idx  = out + 8388608;
    float* out_loss = out + 8388608 + 131072;

    char* w = (char*)d_ws;
    float*          E        = (float*)(w);                    //   4 KB
    unsigned short* e_swz    = (unsigned short*)(w + 4096);    // 256 KB
    int*            bestk    = (int*)(w + 266240);             // 512 KB
    int*            flagA    = (int*)(w + 790528);             // 512 KB
    int*            list     = (int*)(w + 1314816);            // 512 KB
    int*            cnt      = (int*)(w + 1839104);            //   4 B
    float*          partials = (float*)(w + 1840128);          //   4 KB

    vq_prep<<<32, 256, 0, stream>>>(emb, e_swz, E, cnt);
    vq_scan_mfma<<<NPTS / 128, 256, 0, stream>>>(z_e, e_swz, E, bestk, flagA);
    vq_compact<<<NPTS / 256, 256, 0, stream>>>(flagA, list, cnt);
    vq_rescue<<<2048, 256, 0, stream>>>(z_e, emb, E, list, cnt, bestk);
    vq_merge<<<NPTS / 128, 256, 0, stream>>>(z_e, emb, bestk, out_q, out_idx, partials);
    vq_loss_fin<<<1, 1024, 0, stream>>>(partials, out_loss);
}

// Round 18
// 115.883 us; speedup vs baseline: 1.4153x; 1.4153x over previous
//
#include <hip/hip_runtime.h>

// VQ codebook: z_e [32,64,64,64] f32 (B,C,W,H), emb [1024,64] f32.
// Outputs: quantized [32,64,64,64] f32, indices [131072] (as f32), vq_loss [1].
//
// R18 = R12 (best: 153.9us) + two cuts:
//  - DELTA 0.02 -> 0.008. Error bound: score err <= 2*(3*2^-18 * sum|e||z|)
//    + accum rounding <= 1.7e-3 (max sum|z| over 131k N(0,1) points ~ 73,
//    |e|<1); certainty needs gap > 2*eps ~ 3.4e-3; 0.008 = 2.3x margin.
//    Rescue set shrinks ~2.5x, still covers all uncertain points -> exact.
//  - compact fused into scan (R13 fusion-1 only; its regression was the
//    threadfence merge-fusion): flagged points atomicAdd-append to list at
//    flag time. 6 -> 5 dispatches.
// Scan compute/epilogue arithmetic bit-identical to R12 (8 variants all
// ~70us; VALU-busy constant ~40us -> locally converged).

#define CDIM   64
#define KCODES 1024
#define NPTS   131072
#define WH     4096
#define CWH    262144
#define CTILES (KCODES / 16)     // 64
#define DELTA  0.008f

typedef __attribute__((ext_vector_type(4))) float f32x4;
typedef __attribute__((ext_vector_type(8))) short bf16x8;
typedef __attribute__((ext_vector_type(8))) unsigned short u16x8;

__device__ inline unsigned short f2bf(float f) {
    unsigned u = __float_as_uint(f);
    return (unsigned short)((u + 0x7FFFu + ((u >> 16) & 1u)) >> 16);
}
__device__ inline float bf2f(unsigned short h) {
    return __uint_as_float(((unsigned)h) << 16);
}

// ---------- prep: E (exact R1 order) + wide swizzle + cnt=0 ----------
__global__ __launch_bounds__(256) void vq_prep(const float* __restrict__ emb,
                                               unsigned short* __restrict__ e_swz,
                                               float* __restrict__ E,
                                               int* __restrict__ cnt) {
    const int id = blockIdx.x * 256 + threadIdx.x;
    if (id == 0) cnt[0] = 0;

    if (id < KCODES) {   // E[c], bit-identical to R1
        const int c = id;
        const float4* e4 = (const float4*)(emb + c * CDIM);
        float s = 0.f;
#pragma unroll
        for (int i = 0; i < CDIM / 4; ++i) {
            float4 v = e4[i];
            s = fmaf(v.x, v.x, s); s = fmaf(v.y, v.y, s);
            s = fmaf(v.z, v.z, s); s = fmaf(v.w, v.w, s);
        }
        E[c] = s;
    }

    if (id < KCODES * 8) {
        const int c  = id >> 3;
        const int kh = (id >> 2) & 1;
        const int g  = id & 3;
        const int ct = c >> 4, col = c & 15;
        const int lane = (g << 4) | col;
        const size_t bh = ((size_t)(ct * 2 + 0) * 2 + kh) * 512 + (size_t)lane * 8;
        const size_t bl = ((size_t)(ct * 2 + 1) * 2 + kh) * 512 + (size_t)lane * 8;
        u16x8 his, los;
#pragma unroll
        for (int j = 0; j < 8; ++j) {
            float v = emb[c * CDIM + kh * 32 + g * 8 + j];
            unsigned short hi = f2bf(v);
            unsigned short lo = f2bf(v - bf2f(hi));
            his[j] = hi;
            los[j] = lo;
        }
        *(u16x8*)&e_swz[bh] = his;
        *(u16x8*)&e_swz[bl] = los;
    }
}

// ---------- MFMA scan (R12 compute verbatim) + inline list append ----------
__global__ __launch_bounds__(256) void vq_scan_mfma(const float* __restrict__ z_e,
                                                    const unsigned short* __restrict__ e_swz,
                                                    const float* __restrict__ E,
                                                    int* __restrict__ bestk,
                                                    int* __restrict__ list,
                                                    int* __restrict__ cnt) {
    const int tid = threadIdx.x;
    const int n0  = blockIdx.x * 128;
    const int b   = n0 >> 12;
    const int wh0 = n0 & 4095;

    __shared__ unsigned short zfrag[8][2][2][512];   // 32 KB

    const float* zp = z_e + (size_t)b * CWH + wh0;
#pragma unroll 4
    for (int i = 0; i < 32; ++i) {
        int flat = i * 256 + tid;
        int c = flat >> 7, p = flat & 127;
        float v = zp[(size_t)c * WH + p];
        unsigned short hi = f2bf(v);
        unsigned short lo = f2bf(v - bf2f(hi));
        int slot = ((((c & 31) >> 3) << 4) | (p & 15)) * 8 + (c & 7);
        zfrag[p >> 4][0][c >> 5][slot] = hi;
        zfrag[p >> 4][1][c >> 5][slot] = lo;
    }
    __syncthreads();

    const int lane = tid & 63;
    const int w    = tid >> 6;

    bf16x8 zf[2][2][2];
#pragma unroll
    for (int pt = 0; pt < 2; ++pt)
#pragma unroll
        for (int s = 0; s < 2; ++s)
#pragma unroll
            for (int kh = 0; kh < 2; ++kh)
                zf[pt][s][kh] = *(const bf16x8*)&zfrag[2 * w + pt][s][kh][lane * 8];

    const bf16x8* ebv = (const bf16x8*)e_swz;
    const int eoff = ((lane >> 4) << 2);

    float m1a = 1e30f, m2a = 1e30f; int k1a = 0;
    float m1b = 1e30f, m2b = 1e30f; int k1b = 0;

    bf16x8 eh0 = ebv[0 * 64 + lane];
    bf16x8 eh1 = ebv[1 * 64 + lane];
    bf16x8 el0 = ebv[2 * 64 + lane];
    bf16x8 el1 = ebv[3 * 64 + lane];
    f32x4  Ev  = *(const f32x4*)(E + eoff);

    for (int ct = 0; ct < CTILES; ++ct) {
        const int ctn = (ct + 1) & 63;
        bf16x8 p0 = ebv[(ctn * 4 + 0) * 64 + lane];
        bf16x8 p1 = ebv[(ctn * 4 + 1) * 64 + lane];
        bf16x8 p2 = ebv[(ctn * 4 + 2) * 64 + lane];
        bf16x8 p3 = ebv[(ctn * 4 + 3) * 64 + lane];
        f32x4  Ep = *(const f32x4*)(E + ctn * 16 + eoff);

        f32x4 acc0 = {0.f, 0.f, 0.f, 0.f};
        f32x4 acc1 = {0.f, 0.f, 0.f, 0.f};
        acc0 = __builtin_amdgcn_mfma_f32_16x16x32_bf16(eh0, zf[0][0][0], acc0, 0, 0, 0);
        acc0 = __builtin_amdgcn_mfma_f32_16x16x32_bf16(eh1, zf[0][0][1], acc0, 0, 0, 0);
        acc0 = __builtin_amdgcn_mfma_f32_16x16x32_bf16(eh0, zf[0][1][0], acc0, 0, 0, 0);
        acc0 = __builtin_amdgcn_mfma_f32_16x16x32_bf16(eh1, zf[0][1][1], acc0, 0, 0, 0);
        acc0 = __builtin_amdgcn_mfma_f32_16x16x32_bf16(el0, zf[0][0][0], acc0, 0, 0, 0);
        acc0 = __builtin_amdgcn_mfma_f32_16x16x32_bf16(el1, zf[0][0][1], acc0, 0, 0, 0);
        acc1 = __builtin_amdgcn_mfma_f32_16x16x32_bf16(eh0, zf[1][0][0], acc1, 0, 0, 0);
        acc1 = __builtin_amdgcn_mfma_f32_16x16x32_bf16(eh1, zf[1][0][1], acc1, 0, 0, 0);
        acc1 = __builtin_amdgcn_mfma_f32_16x16x32_bf16(eh0, zf[1][1][0], acc1, 0, 0, 0);
        acc1 = __builtin_amdgcn_mfma_f32_16x16x32_bf16(eh1, zf[1][1][1], acc1, 0, 0, 0);
        acc1 = __builtin_amdgcn_mfma_f32_16x16x32_bf16(el0, zf[1][0][0], acc1, 0, 0, 0);
        acc1 = __builtin_amdgcn_mfma_f32_16x16x32_bf16(el1, zf[1][0][1], acc1, 0, 0, 0);

        const int kb = ct * 16 + eoff;
#pragma unroll
        for (int i = 0; i < 4; ++i) {
            float s0 = fmaf(-2.0f, acc0[i], Ev[i]);
            if (s0 < m1a) { m2a = m1a; m1a = s0; k1a = kb + i; } else m2a = fminf(m2a, s0);
            float s1 = fmaf(-2.0f, acc1[i], Ev[i]);
            if (s1 < m1b) { m2b = m1b; m1b = s1; k1b = kb + i; } else m2b = fminf(m2b, s1);
        }

        eh0 = p0; eh1 = p1; el0 = p2; el1 = p3; Ev = Ep;
    }

#pragma unroll
    for (int d = 16; d <= 32; d <<= 1) {
        float om1 = __shfl_xor(m1a, d); int ok1 = __shfl_xor(k1a, d); float om2 = __shfl_xor(m2a, d);
        bool take = (om1 < m1a) || (om1 == m1a && ok1 < k1a);
        float nm2 = take ? fminf(m1a, om2) : fminf(m2a, om1);
        if (take) { m1a = om1; k1a = ok1; }
        m2a = nm2;
        om1 = __shfl_xor(m1b, d); ok1 = __shfl_xor(k1b, d); om2 = __shfl_xor(m2b, d);
        take = (om1 < m1b) || (om1 == m1b && ok1 < k1b);
        nm2 = take ? fminf(m1b, om2) : fminf(m2b, om1);
        if (take) { m1b = om1; k1b = ok1; }
        m2b = nm2;
    }

    if (lane < 16) {
        int na  = n0 + (2 * w + 0) * 16 + lane;
        int nb_ = n0 + (2 * w + 1) * 16 + lane;
        bestk[na]  = k1a;
        bestk[nb_] = k1b;
        // fused compact: append flagged (uncertain) points
        if (m2a - m1a <= DELTA) { int p = atomicAdd(cnt, 1); list[p] = na; }
        if (m2b - m1b <= DELTA) { int p = atomicAdd(cnt, 1); list[p] = nb_; }
    }
}

// ---------- rescue (R12 verbatim): wave-parallel exact f32 rescan ----------
__global__ __launch_bounds__(256) void vq_rescue(const float* __restrict__ z_e,
                                                 const float* __restrict__ emb,
                                                 const float* __restrict__ E,
                                                 const int* __restrict__ list,
                                                 const int* __restrict__ cnt,
                                                 int* __restrict__ bestk) {
    const int total  = cnt[0];
    const int lane   = threadIdx.x & 63;
    const int wid    = (blockIdx.x * 256 + threadIdx.x) >> 6;
    const int nwaves = (gridDim.x * 256) >> 6;

    for (int i = wid; i < total; i += nwaves) {
        const int n  = list[i];
        const int b  = n >> 12, wh = n & 4095;
        const float* zp = z_e + (size_t)b * CWH + wh;
        float z[CDIM];
#pragma unroll
        for (int c = 0; c < CDIM; ++c) z[c] = zp[c * WH];

        float best = 1e30f; int bk = 0;
        const int kbase = lane * 16;
#pragma unroll 4
        for (int j = 0; j < 16; ++j) {
            const int k = kbase + j;
            const float4* er4 = (const float4*)(emb + k * CDIM);
            float d0 = 0.f, d1 = 0.f, d2 = 0.f, d3 = 0.f;
#pragma unroll
            for (int c4 = 0; c4 < CDIM / 4; ++c4) {
                float4 v = er4[c4];
                d0 = fmaf(z[4 * c4 + 0], v.x, d0);
                d1 = fmaf(z[4 * c4 + 1], v.y, d1);
                d2 = fmaf(z[4 * c4 + 2], v.z, d2);
                d3 = fmaf(z[4 * c4 + 3], v.w, d3);
            }
            float dot   = (d0 + d1) + (d2 + d3);
            float score = fmaf(-2.0f, dot, E[k]);
            if (score < best) { best = score; bk = k; }
        }
#pragma unroll
        for (int d = 1; d < 64; d <<= 1) {
            float ob = __shfl_xor(best, d);
            int   ok = __shfl_xor(bk, d);
            if (ob < best || (ob == best && ok < bk)) { best = ob; bk = ok; }
        }
        if (lane == 0) bestk[n] = bk;
    }
}

// ---------- merge: 4 consecutive points x 8 channels per thread (R12 verbatim) ----------
__global__ __launch_bounds__(256) void vq_merge(const float* __restrict__ z_e,
                                                const float* __restrict__ emb,
                                                const int* __restrict__ kf,
                                                float* __restrict__ out_q,
                                                float* __restrict__ out_idx,
                                                float* __restrict__ partials) {
    const int tid = threadIdx.x;
    const int cq  = tid >> 5;            // 0..7 -> channels cq*8 .. cq*8+7
    const int pq  = tid & 31;            // 4 consecutive points
    const int n0  = blockIdx.x * 128 + pq * 4;
    const int b   = n0 >> 12;
    const int wh  = n0 & 4095;

    const int4 mk4 = *(const int4*)&kf[n0];
    if (cq == 0) {
        float4 fx = { (float)mk4.x, (float)mk4.y, (float)mk4.z, (float)mk4.w };
        *(float4*)&out_idx[n0] = fx;
    }

    const float* zb = z_e   + (size_t)b * CWH + wh;
    float*       qb = out_q + (size_t)b * CWH + wh;
    const int c0 = cq * 8;
    float lsum = 0.f;
#pragma unroll
    for (int cc = 0; cc < 8; ++cc) {
        const int c = c0 + cc;
        float4 z4 = *(const float4*)&zb[(size_t)c * WH];
        float4 q4;
        q4.x = emb[mk4.x * CDIM + c];
        q4.y = emb[mk4.y * CDIM + c];
        q4.z = emb[mk4.z * CDIM + c];
        q4.w = emb[mk4.w * CDIM + c];
        *(float4*)&qb[(size_t)c * WH] = q4;
        float dx = q4.x - z4.x, dy = q4.y - z4.y;
        float dz = q4.z - z4.z, dw = q4.w - z4.w;
        lsum = fmaf(dx, dx, lsum); lsum = fmaf(dy, dy, lsum);
        lsum = fmaf(dz, dz, lsum); lsum = fmaf(dw, dw, lsum);
    }

    __shared__ float red[256];
    red[tid] = lsum;
    __syncthreads();
    for (int s = 128; s > 0; s >>= 1) {
        if (tid < s) red[tid] += red[tid + s];
        __syncthreads();
    }
    if (tid == 0) partials[blockIdx.x] = red[0];
}

__global__ __launch_bounds__(1024) void vq_loss_fin(const float* __restrict__ partials,
                                                    float* __restrict__ loss) {
    __shared__ float red[1024];
    int t = threadIdx.x;
    red[t] = partials[t];
    __syncthreads();
    for (int s = 512; s > 0; s >>= 1) {
        if (t < s) red[t] += red[t + s];
        __syncthreads();
    }
    if (t == 0) loss[0] = red[0] * (1.25f / 8388608.0f);
}

extern "C" void kernel_launch(void* const* d_in, const int* in_sizes, int n_in,
                              void* d_out, int out_size, void* d_ws, size_t ws_size,
                              hipStream_t stream) {
    const float* z_e = (const float*)d_in[0];
    const float* emb = (const float*)d_in[1];

    float* out      = (float*)d_out;
    float* out_q    = out;
    float* out_idx  = out + 8388608;
    float* out_loss = out + 8388608 + 131072;

    char* w = (char*)d_ws;
    float*          E        = (float*)(w);                    //   4 KB
    unsigned short* e_swz    = (unsigned short*)(w + 4096);    // 256 KB
    int*            bestk    = (int*)(w + 266240);             // 512 KB
    int*            list     = (int*)(w + 790528);             // 512 KB
    int*            cnt      = (int*)(w + 1314816);            //   4 B
    float*          partials = (float*)(w + 1315840);          //   4 KB

    vq_prep<<<32, 256, 0, stream>>>(emb, e_swz, E, cnt);
    vq_scan_mfma<<<NPTS / 128, 256, 0, stream>>>(z_e, e_swz, E, bestk, list, cnt);
    vq_rescue<<<2048, 256, 0, stream>>>(z_e, emb, E, list, cnt, bestk);
    vq_merge<<<NPTS / 128, 256, 0, stream>>>(z_e, emb, bestk, out_q, out_idx, partials);
    vq_loss_fin<<<1, 1024, 0, stream>>>(partials, out_loss);
}

// Round 19
// 115.027 us; speedup vs baseline: 1.4259x; 1.0074x over previous
//
#include <hip/hip_runtime.h>

// VQ codebook: z_e [32,64,64,64] f32 (B,C,W,H), emb [1024,64] f32.
// Outputs: quantized [32,64,64,64] f32, indices [131072] (as f32), vq_loss [1].
//
// R19 = R18 (115.9us) + merge gather vectorization: each thread loads its 4
// points' emb rows as float4 pairs (8 vector gathers) instead of 32 scalar
// gathers (64 scattered 4B addrs/instr was L1-serialized), register-
// transposes, and emits the same float4 q writes. q/idx values bitwise
// identical; per-thread loss fmaf order changes (mean, ~1e-6, allowed).
// Everything else R18 verbatim.

#define CDIM   64
#define KCODES 1024
#define NPTS   131072
#define WH     4096
#define CWH    262144
#define CTILES (KCODES / 16)     // 64
#define DELTA  0.008f

typedef __attribute__((ext_vector_type(4))) float f32x4;
typedef __attribute__((ext_vector_type(8))) short bf16x8;
typedef __attribute__((ext_vector_type(8))) unsigned short u16x8;

__device__ inline unsigned short f2bf(float f) {
    unsigned u = __float_as_uint(f);
    return (unsigned short)((u + 0x7FFFu + ((u >> 16) & 1u)) >> 16);
}
__device__ inline float bf2f(unsigned short h) {
    return __uint_as_float(((unsigned)h) << 16);
}

// ---------- prep: E (exact R1 order) + wide swizzle + cnt=0 (R18 verbatim) ----------
__global__ __launch_bounds__(256) void vq_prep(const float* __restrict__ emb,
                                               unsigned short* __restrict__ e_swz,
                                               float* __restrict__ E,
                                               int* __restrict__ cnt) {
    const int id = blockIdx.x * 256 + threadIdx.x;
    if (id == 0) cnt[0] = 0;

    if (id < KCODES) {   // E[c], bit-identical to R1
        const int c = id;
        const float4* e4 = (const float4*)(emb + c * CDIM);
        float s = 0.f;
#pragma unroll
        for (int i = 0; i < CDIM / 4; ++i) {
            float4 v = e4[i];
            s = fmaf(v.x, v.x, s); s = fmaf(v.y, v.y, s);
            s = fmaf(v.z, v.z, s); s = fmaf(v.w, v.w, s);
        }
        E[c] = s;
    }

    if (id < KCODES * 8) {
        const int c  = id >> 3;
        const int kh = (id >> 2) & 1;
        const int g  = id & 3;
        const int ct = c >> 4, col = c & 15;
        const int lane = (g << 4) | col;
        const size_t bh = ((size_t)(ct * 2 + 0) * 2 + kh) * 512 + (size_t)lane * 8;
        const size_t bl = ((size_t)(ct * 2 + 1) * 2 + kh) * 512 + (size_t)lane * 8;
        u16x8 his, los;
#pragma unroll
        for (int j = 0; j < 8; ++j) {
            float v = emb[c * CDIM + kh * 32 + g * 8 + j];
            unsigned short hi = f2bf(v);
            unsigned short lo = f2bf(v - bf2f(hi));
            his[j] = hi;
            los[j] = lo;
        }
        *(u16x8*)&e_swz[bh] = his;
        *(u16x8*)&e_swz[bl] = los;
    }
}

// ---------- MFMA scan (R18 verbatim): R12 compute + inline list append ----------
__global__ __launch_bounds__(256) void vq_scan_mfma(const float* __restrict__ z_e,
                                                    const unsigned short* __restrict__ e_swz,
                                                    const float* __restrict__ E,
                                                    int* __restrict__ bestk,
                                                    int* __restrict__ list,
                                                    int* __restrict__ cnt) {
    const int tid = threadIdx.x;
    const int n0  = blockIdx.x * 128;
    const int b   = n0 >> 12;
    const int wh0 = n0 & 4095;

    __shared__ unsigned short zfrag[8][2][2][512];   // 32 KB

    const float* zp = z_e + (size_t)b * CWH + wh0;
#pragma unroll 4
    for (int i = 0; i < 32; ++i) {
        int flat = i * 256 + tid;
        int c = flat >> 7, p = flat & 127;
        float v = zp[(size_t)c * WH + p];
        unsigned short hi = f2bf(v);
        unsigned short lo = f2bf(v - bf2f(hi));
        int slot = ((((c & 31) >> 3) << 4) | (p & 15)) * 8 + (c & 7);
        zfrag[p >> 4][0][c >> 5][slot] = hi;
        zfrag[p >> 4][1][c >> 5][slot] = lo;
    }
    __syncthreads();

    const int lane = tid & 63;
    const int w    = tid >> 6;

    bf16x8 zf[2][2][2];
#pragma unroll
    for (int pt = 0; pt < 2; ++pt)
#pragma unroll
        for (int s = 0; s < 2; ++s)
#pragma unroll
            for (int kh = 0; kh < 2; ++kh)
                zf[pt][s][kh] = *(const bf16x8*)&zfrag[2 * w + pt][s][kh][lane * 8];

    const bf16x8* ebv = (const bf16x8*)e_swz;
    const int eoff = ((lane >> 4) << 2);

    float m1a = 1e30f, m2a = 1e30f; int k1a = 0;
    float m1b = 1e30f, m2b = 1e30f; int k1b = 0;

    bf16x8 eh0 = ebv[0 * 64 + lane];
    bf16x8 eh1 = ebv[1 * 64 + lane];
    bf16x8 el0 = ebv[2 * 64 + lane];
    bf16x8 el1 = ebv[3 * 64 + lane];
    f32x4  Ev  = *(const f32x4*)(E + eoff);

    for (int ct = 0; ct < CTILES; ++ct) {
        const int ctn = (ct + 1) & 63;
        bf16x8 p0 = ebv[(ctn * 4 + 0) * 64 + lane];
        bf16x8 p1 = ebv[(ctn * 4 + 1) * 64 + lane];
        bf16x8 p2 = ebv[(ctn * 4 + 2) * 64 + lane];
        bf16x8 p3 = ebv[(ctn * 4 + 3) * 64 + lane];
        f32x4  Ep = *(const f32x4*)(E + ctn * 16 + eoff);

        f32x4 acc0 = {0.f, 0.f, 0.f, 0.f};
        f32x4 acc1 = {0.f, 0.f, 0.f, 0.f};
        acc0 = __builtin_amdgcn_mfma_f32_16x16x32_bf16(eh0, zf[0][0][0], acc0, 0, 0, 0);
        acc0 = __builtin_amdgcn_mfma_f32_16x16x32_bf16(eh1, zf[0][0][1], acc0, 0, 0, 0);
        acc0 = __builtin_amdgcn_mfma_f32_16x16x32_bf16(eh0, zf[0][1][0], acc0, 0, 0, 0);
        acc0 = __builtin_amdgcn_mfma_f32_16x16x32_bf16(eh1, zf[0][1][1], acc0, 0, 0, 0);
        acc0 = __builtin_amdgcn_mfma_f32_16x16x32_bf16(el0, zf[0][0][0], acc0, 0, 0, 0);
        acc0 = __builtin_amdgcn_mfma_f32_16x16x32_bf16(el1, zf[0][0][1], acc0, 0, 0, 0);
        acc1 = __builtin_amdgcn_mfma_f32_16x16x32_bf16(eh0, zf[1][0][0], acc1, 0, 0, 0);
        acc1 = __builtin_amdgcn_mfma_f32_16x16x32_bf16(eh1, zf[1][0][1], acc1, 0, 0, 0);
        acc1 = __builtin_amdgcn_mfma_f32_16x16x32_bf16(eh0, zf[1][1][0], acc1, 0, 0, 0);
        acc1 = __builtin_amdgcn_mfma_f32_16x16x32_bf16(eh1, zf[1][1][1], acc1, 0, 0, 0);
        acc1 = __builtin_amdgcn_mfma_f32_16x16x32_bf16(el0, zf[1][0][0], acc1, 0, 0, 0);
        acc1 = __builtin_amdgcn_mfma_f32_16x16x32_bf16(el1, zf[1][0][1], acc1, 0, 0, 0);

        const int kb = ct * 16 + eoff;
#pragma unroll
        for (int i = 0; i < 4; ++i) {
            float s0 = fmaf(-2.0f, acc0[i], Ev[i]);
            if (s0 < m1a) { m2a = m1a; m1a = s0; k1a = kb + i; } else m2a = fminf(m2a, s0);
            float s1 = fmaf(-2.0f, acc1[i], Ev[i]);
            if (s1 < m1b) { m2b = m1b; m1b = s1; k1b = kb + i; } else m2b = fminf(m2b, s1);
        }

        eh0 = p0; eh1 = p1; el0 = p2; el1 = p3; Ev = Ep;
    }

#pragma unroll
    for (int d = 16; d <= 32; d <<= 1) {
        float om1 = __shfl_xor(m1a, d); int ok1 = __shfl_xor(k1a, d); float om2 = __shfl_xor(m2a, d);
        bool take = (om1 < m1a) || (om1 == m1a && ok1 < k1a);
        float nm2 = take ? fminf(m1a, om2) : fminf(m2a, om1);
        if (take) { m1a = om1; k1a = ok1; }
        m2a = nm2;
        om1 = __shfl_xor(m1b, d); ok1 = __shfl_xor(k1b, d); om2 = __shfl_xor(m2b, d);
        take = (om1 < m1b) || (om1 == m1b && ok1 < k1b);
        nm2 = take ? fminf(m1b, om2) : fminf(m2b, om1);
        if (take) { m1b = om1; k1b = ok1; }
        m2b = nm2;
    }

    if (lane < 16) {
        int na  = n0 + (2 * w + 0) * 16 + lane;
        int nb_ = n0 + (2 * w + 1) * 16 + lane;
        bestk[na]  = k1a;
        bestk[nb_] = k1b;
        if (m2a - m1a <= DELTA) { int p = atomicAdd(cnt, 1); list[p] = na; }
        if (m2b - m1b <= DELTA) { int p = atomicAdd(cnt, 1); list[p] = nb_; }
    }
}

// ---------- rescue (R18 verbatim): wave-parallel exact f32 rescan ----------
__global__ __launch_bounds__(256) void vq_rescue(const float* __restrict__ z_e,
                                                 const float* __restrict__ emb,
                                                 const float* __restrict__ E,
                                                 const int* __restrict__ list,
                                                 const int* __restrict__ cnt,
                                                 int* __restrict__ bestk) {
    const int total  = cnt[0];
    const int lane   = threadIdx.x & 63;
    const int wid    = (blockIdx.x * 256 + threadIdx.x) >> 6;
    const int nwaves = (gridDim.x * 256) >> 6;

    for (int i = wid; i < total; i += nwaves) {
        const int n  = list[i];
        const int b  = n >> 12, wh = n & 4095;
        const float* zp = z_e + (size_t)b * CWH + wh;
        float z[CDIM];
#pragma unroll
        for (int c = 0; c < CDIM; ++c) z[c] = zp[c * WH];

        float best = 1e30f; int bk = 0;
        const int kbase = lane * 16;
#pragma unroll 4
        for (int j = 0; j < 16; ++j) {
            const int k = kbase + j;
            const float4* er4 = (const float4*)(emb + k * CDIM);
            float d0 = 0.f, d1 = 0.f, d2 = 0.f, d3 = 0.f;
#pragma unroll
            for (int c4 = 0; c4 < CDIM / 4; ++c4) {
                float4 v = er4[c4];
                d0 = fmaf(z[4 * c4 + 0], v.x, d0);
                d1 = fmaf(z[4 * c4 + 1], v.y, d1);
                d2 = fmaf(z[4 * c4 + 2], v.z, d2);
                d3 = fmaf(z[4 * c4 + 3], v.w, d3);
            }
            float dot   = (d0 + d1) + (d2 + d3);
            float score = fmaf(-2.0f, dot, E[k]);
            if (score < best) { best = score; bk = k; }
        }
#pragma unroll
        for (int d = 1; d < 64; d <<= 1) {
            float ob = __shfl_xor(best, d);
            int   ok = __shfl_xor(bk, d);
            if (ob < best || (ob == best && ok < bk)) { best = ob; bk = ok; }
        }
        if (lane == 0) bestk[n] = bk;
    }
}

// ---------- merge: 4 points x 8 channels/thread, VECTOR emb gathers ----------
__global__ __launch_bounds__(256) void vq_merge(const float* __restrict__ z_e,
                                                const float* __restrict__ emb,
                                                const int* __restrict__ kf,
                                                float* __restrict__ out_q,
                                                float* __restrict__ out_idx,
                                                float* __restrict__ partials) {
    const int tid = threadIdx.x;
    const int cq  = tid >> 5;            // 0..7 -> channels cq*8 .. cq*8+7
    const int pq  = tid & 31;            // 4 consecutive points
    const int n0  = blockIdx.x * 128 + pq * 4;
    const int b   = n0 >> 12;
    const int wh  = n0 & 4095;

    const int4 mk4 = *(const int4*)&kf[n0];
    if (cq == 0) {
        float4 fx = { (float)mk4.x, (float)mk4.y, (float)mk4.z, (float)mk4.w };
        *(float4*)&out_idx[n0] = fx;
    }

    const int c0 = cq * 8;
    // Vector gathers: 2 float4 per point (channels c0..c0+3, c0+4..c0+7).
    float4 e0a = *(const float4*)&emb[mk4.x * CDIM + c0];
    float4 e0b = *(const float4*)&emb[mk4.x * CDIM + c0 + 4];
    float4 e1a = *(const float4*)&emb[mk4.y * CDIM + c0];
    float4 e1b = *(const float4*)&emb[mk4.y * CDIM + c0 + 4];
    float4 e2a = *(const float4*)&emb[mk4.z * CDIM + c0];
    float4 e2b = *(const float4*)&emb[mk4.z * CDIM + c0 + 4];
    float4 e3a = *(const float4*)&emb[mk4.w * CDIM + c0];
    float4 e3b = *(const float4*)&emb[mk4.w * CDIM + c0 + 4];

    // Register transpose into per-channel rows q[cc] = {pt0,pt1,pt2,pt3}.
    float qv[8][4];
    qv[0][0] = e0a.x; qv[0][1] = e1a.x; qv[0][2] = e2a.x; qv[0][3] = e3a.x;
    qv[1][0] = e0a.y; qv[1][1] = e1a.y; qv[1][2] = e2a.y; qv[1][3] = e3a.y;
    qv[2][0] = e0a.z; qv[2][1] = e1a.z; qv[2][2] = e2a.z; qv[2][3] = e3a.z;
    qv[3][0] = e0a.w; qv[3][1] = e1a.w; qv[3][2] = e2a.w; qv[3][3] = e3a.w;
    qv[4][0] = e0b.x; qv[4][1] = e1b.x; qv[4][2] = e2b.x; qv[4][3] = e3b.x;
    qv[5][0] = e0b.y; qv[5][1] = e1b.y; qv[5][2] = e2b.y; qv[5][3] = e3b.y;
    qv[6][0] = e0b.z; qv[6][1] = e1b.z; qv[6][2] = e2b.z; qv[6][3] = e3b.z;
    qv[7][0] = e0b.w; qv[7][1] = e1b.w; qv[7][2] = e2b.w; qv[7][3] = e3b.w;

    const float* zb = z_e   + (size_t)b * CWH + wh;
    float*       qb = out_q + (size_t)b * CWH + wh;
    float lsum = 0.f;
#pragma unroll
    for (int cc = 0; cc < 8; ++cc) {
        const int c = c0 + cc;
        float4 z4 = *(const float4*)&zb[(size_t)c * WH];
        float4 q4 = { qv[cc][0], qv[cc][1], qv[cc][2], qv[cc][3] };
        *(float4*)&qb[(size_t)c * WH] = q4;
        float dx = q4.x - z4.x, dy = q4.y - z4.y;
        float dz = q4.z - z4.z, dw = q4.w - z4.w;
        lsum = fmaf(dx, dx, lsum); lsum = fmaf(dy, dy, lsum);
        lsum = fmaf(dz, dz, lsum); lsum = fmaf(dw, dw, lsum);
    }

    __shared__ float red[256];
    red[tid] = lsum;
    __syncthreads();
    for (int s = 128; s > 0; s >>= 1) {
        if (tid < s) red[tid] += red[tid + s];
        __syncthreads();
    }
    if (tid == 0) partials[blockIdx.x] = red[0];
}

__global__ __launch_bounds__(1024) void vq_loss_fin(const float* __restrict__ partials,
                                                    float* __restrict__ loss) {
    __shared__ float red[1024];
    int t = threadIdx.x;
    red[t] = partials[t];
    __syncthreads();
    for (int s = 512; s > 0; s >>= 1) {
        if (t < s) red[t] += red[t + s];
        __syncthreads();
    }
    if (t == 0) loss[0] = red[0] * (1.25f / 8388608.0f);
}

extern "C" void kernel_launch(void* const* d_in, const int* in_sizes, int n_in,
                              void* d_out, int out_size, void* d_ws, size_t ws_size,
                              hipStream_t stream) {
    const float* z_e = (const float*)d_in[0];
    const float* emb = (const float*)d_in[1];

    float* out      = (float*)d_out;
    float* out_q    = out;
    float* out_idx  = out + 8388608;
    float* out_loss = out + 8388608 + 131072;

    char* w = (char*)d_ws;
    float*          E        = (float*)(w);                    //   4 KB
    unsigned short* e_swz    = (unsigned short*)(w + 4096);    // 256 KB
    int*            bestk    = (int*)(w + 266240);             // 512 KB
    int*            list     = (int*)(w + 790528);             // 512 KB
    int*            cnt      = (int*)(w + 1314816);            //   4 B
    float*          partials = (float*)(w + 1315840);          //   4 KB

    vq_prep<<<32, 256, 0, stream>>>(emb, e_swz, E, cnt);
    vq_scan_mfma<<<NPTS / 128, 256, 0, stream>>>(z_e, e_swz, E, bestk, list, cnt);
    vq_rescue<<<2048, 256, 0, stream>>>(z_e, emb, E, list, cnt, bestk);
    vq_merge<<<NPTS / 128, 256, 0, stream>>>(z_e, emb, bestk, out_q, out_idx, partials);
    vq_loss_fin<<<1, 1024, 0, stream>>>(partials, out_loss);
}

// Round 20
// 114.739 us; speedup vs baseline: 1.4295x; 1.0025x over previous
//
#include <hip/hip_runtime.h>

// VQ codebook: z_e [32,64,64,64] f32 (B,C,W,H), emb [1024,64] f32.
// Outputs: quantized [32,64,64,64] f32, indices [131072] (as f32), vq_loss [1].
//
// R20 = R19 + scan epilogue de-serialization: 4 independent (m1,m2,k1)
// trackers per point (one per acc slot i) instead of one loop-carried chain
// through all 512 updates. ILP 8 vs 2 on the min-update spine (the suspected
// 40us VALU-stall source across 8 pinned variants). Post-loop lexicographic
// (score,k) tournament merge -> m1/m2/k1 values identical to the sequential
// scan (min/second-min are order-independent; first-min k via explicit k<
// tie-break). Flags, rescue set, indices unchanged. Everything else R19.

#define CDIM   64
#define KCODES 1024
#define NPTS   131072
#define WH     4096
#define CWH    262144
#define CTILES (KCODES / 16)     // 64
#define DELTA  0.008f

typedef __attribute__((ext_vector_type(4))) float f32x4;
typedef __attribute__((ext_vector_type(8))) short bf16x8;
typedef __attribute__((ext_vector_type(8))) unsigned short u16x8;

__device__ inline unsigned short f2bf(float f) {
    unsigned u = __float_as_uint(f);
    return (unsigned short)((u + 0x7FFFu + ((u >> 16) & 1u)) >> 16);
}
__device__ inline float bf2f(unsigned short h) {
    return __uint_as_float(((unsigned)h) << 16);
}

// ---------- prep: E (exact R1 order) + wide swizzle + cnt=0 (R19 verbatim) ----------
__global__ __launch_bounds__(256) void vq_prep(const float* __restrict__ emb,
                                               unsigned short* __restrict__ e_swz,
                                               float* __restrict__ E,
                                               int* __restrict__ cnt) {
    const int id = blockIdx.x * 256 + threadIdx.x;
    if (id == 0) cnt[0] = 0;

    if (id < KCODES) {   // E[c], bit-identical to R1
        const int c = id;
        const float4* e4 = (const float4*)(emb + c * CDIM);
        float s = 0.f;
#pragma unroll
        for (int i = 0; i < CDIM / 4; ++i) {
            float4 v = e4[i];
            s = fmaf(v.x, v.x, s); s = fmaf(v.y, v.y, s);
            s = fmaf(v.z, v.z, s); s = fmaf(v.w, v.w, s);
        }
        E[c] = s;
    }

    if (id < KCODES * 8) {
        const int c  = id >> 3;
        const int kh = (id >> 2) & 1;
        const int g  = id & 3;
        const int ct = c >> 4, col = c & 15;
        const int lane = (g << 4) | col;
        const size_t bh = ((size_t)(ct * 2 + 0) * 2 + kh) * 512 + (size_t)lane * 8;
        const size_t bl = ((size_t)(ct * 2 + 1) * 2 + kh) * 512 + (size_t)lane * 8;
        u16x8 his, los;
#pragma unroll
        for (int j = 0; j < 8; ++j) {
            float v = emb[c * CDIM + kh * 32 + g * 8 + j];
            unsigned short hi = f2bf(v);
            unsigned short lo = f2bf(v - bf2f(hi));
            his[j] = hi;
            los[j] = lo;
        }
        *(u16x8*)&e_swz[bh] = his;
        *(u16x8*)&e_swz[bl] = los;
    }
}

// ---------- MFMA scan: R19 structure, per-slot independent min-trackers ----------
__global__ __launch_bounds__(256) void vq_scan_mfma(const float* __restrict__ z_e,
                                                    const unsigned short* __restrict__ e_swz,
                                                    const float* __restrict__ E,
                                                    int* __restrict__ bestk,
                                                    int* __restrict__ list,
                                                    int* __restrict__ cnt) {
    const int tid = threadIdx.x;
    const int n0  = blockIdx.x * 128;
    const int b   = n0 >> 12;
    const int wh0 = n0 & 4095;

    __shared__ unsigned short zfrag[8][2][2][512];   // 32 KB

    const float* zp = z_e + (size_t)b * CWH + wh0;
#pragma unroll 4
    for (int i = 0; i < 32; ++i) {
        int flat = i * 256 + tid;
        int c = flat >> 7, p = flat & 127;
        float v = zp[(size_t)c * WH + p];
        unsigned short hi = f2bf(v);
        unsigned short lo = f2bf(v - bf2f(hi));
        int slot = ((((c & 31) >> 3) << 4) | (p & 15)) * 8 + (c & 7);
        zfrag[p >> 4][0][c >> 5][slot] = hi;
        zfrag[p >> 4][1][c >> 5][slot] = lo;
    }
    __syncthreads();

    const int lane = tid & 63;
    const int w    = tid >> 6;

    bf16x8 zf[2][2][2];
#pragma unroll
    for (int pt = 0; pt < 2; ++pt)
#pragma unroll
        for (int s = 0; s < 2; ++s)
#pragma unroll
            for (int kh = 0; kh < 2; ++kh)
                zf[pt][s][kh] = *(const bf16x8*)&zfrag[2 * w + pt][s][kh][lane * 8];

    const bf16x8* ebv = (const bf16x8*)e_swz;
    const int eoff = ((lane >> 4) << 2);

    // 4 independent trackers per point (slot i covers codes ct*16+eoff+i).
    float m1a[4], m2a[4], m1b[4], m2b[4];
    int   k1a[4], k1b[4];
#pragma unroll
    for (int i = 0; i < 4; ++i) {
        m1a[i] = 1e30f; m2a[i] = 1e30f; k1a[i] = 0;
        m1b[i] = 1e30f; m2b[i] = 1e30f; k1b[i] = 0;
    }

    bf16x8 eh0 = ebv[0 * 64 + lane];
    bf16x8 eh1 = ebv[1 * 64 + lane];
    bf16x8 el0 = ebv[2 * 64 + lane];
    bf16x8 el1 = ebv[3 * 64 + lane];
    f32x4  Ev  = *(const f32x4*)(E + eoff);

    for (int ct = 0; ct < CTILES; ++ct) {
        const int ctn = (ct + 1) & 63;
        bf16x8 p0 = ebv[(ctn * 4 + 0) * 64 + lane];
        bf16x8 p1 = ebv[(ctn * 4 + 1) * 64 + lane];
        bf16x8 p2 = ebv[(ctn * 4 + 2) * 64 + lane];
        bf16x8 p3 = ebv[(ctn * 4 + 3) * 64 + lane];
        f32x4  Ep = *(const f32x4*)(E + ctn * 16 + eoff);

        f32x4 acc0 = {0.f, 0.f, 0.f, 0.f};
        f32x4 acc1 = {0.f, 0.f, 0.f, 0.f};
        acc0 = __builtin_amdgcn_mfma_f32_16x16x32_bf16(eh0, zf[0][0][0], acc0, 0, 0, 0);
        acc0 = __builtin_amdgcn_mfma_f32_16x16x32_bf16(eh1, zf[0][0][1], acc0, 0, 0, 0);
        acc0 = __builtin_amdgcn_mfma_f32_16x16x32_bf16(eh0, zf[0][1][0], acc0, 0, 0, 0);
        acc0 = __builtin_amdgcn_mfma_f32_16x16x32_bf16(eh1, zf[0][1][1], acc0, 0, 0, 0);
        acc0 = __builtin_amdgcn_mfma_f32_16x16x32_bf16(el0, zf[0][0][0], acc0, 0, 0, 0);
        acc0 = __builtin_amdgcn_mfma_f32_16x16x32_bf16(el1, zf[0][0][1], acc0, 0, 0, 0);
        acc1 = __builtin_amdgcn_mfma_f32_16x16x32_bf16(eh0, zf[1][0][0], acc1, 0, 0, 0);
        acc1 = __builtin_amdgcn_mfma_f32_16x16x32_bf16(eh1, zf[1][0][1], acc1, 0, 0, 0);
        acc1 = __builtin_amdgcn_mfma_f32_16x16x32_bf16(eh0, zf[1][1][0], acc1, 0, 0, 0);
        acc1 = __builtin_amdgcn_mfma_f32_16x16x32_bf16(eh1, zf[1][1][1], acc1, 0, 0, 0);
        acc1 = __builtin_amdgcn_mfma_f32_16x16x32_bf16(el0, zf[1][0][0], acc1, 0, 0, 0);
        acc1 = __builtin_amdgcn_mfma_f32_16x16x32_bf16(el1, zf[1][0][1], acc1, 0, 0, 0);

        const int kb = ct * 16 + eoff;
#pragma unroll
        for (int i = 0; i < 4; ++i) {
            float s0 = fmaf(-2.0f, acc0[i], Ev[i]);
            if (s0 < m1a[i]) { m2a[i] = m1a[i]; m1a[i] = s0; k1a[i] = kb + i; }
            else             { m2a[i] = fminf(m2a[i], s0); }
            float s1 = fmaf(-2.0f, acc1[i], Ev[i]);
            if (s1 < m1b[i]) { m2b[i] = m1b[i]; m1b[i] = s1; k1b[i] = kb + i; }
            else             { m2b[i] = fminf(m2b[i], s1); }
        }

        eh0 = p0; eh1 = p1; el0 = p2; el1 = p3; Ev = Ep;
    }

    // Merge 4 trackers per point: lexicographic (score, k) tournament.
    // min / second-min are order-independent; k tie-break -> global first-min.
    float m1A = m1a[0], m2A = m2a[0]; int k1A = k1a[0];
    float m1B = m1b[0], m2B = m2b[0]; int k1B = k1b[0];
#pragma unroll
    for (int i = 1; i < 4; ++i) {
        bool take = (m1a[i] < m1A) || (m1a[i] == m1A && k1a[i] < k1A);
        float nm2 = take ? fminf(m1A, m2a[i]) : fminf(m2A, m1a[i]);
        if (take) { m1A = m1a[i]; k1A = k1a[i]; }
        m2A = nm2;
        take = (m1b[i] < m1B) || (m1b[i] == m1B && k1b[i] < k1B);
        nm2 = take ? fminf(m1B, m2b[i]) : fminf(m2B, m1b[i]);
        if (take) { m1B = m1b[i]; k1B = k1b[i]; }
        m2B = nm2;
    }

#pragma unroll
    for (int d = 16; d <= 32; d <<= 1) {
        float om1 = __shfl_xor(m1A, d); int ok1 = __shfl_xor(k1A, d); float om2 = __shfl_xor(m2A, d);
        bool take = (om1 < m1A) || (om1 == m1A && ok1 < k1A);
        float nm2 = take ? fminf(m1A, om2) : fminf(m2A, om1);
        if (take) { m1A = om1; k1A = ok1; }
        m2A = nm2;
        om1 = __shfl_xor(m1B, d); ok1 = __shfl_xor(k1B, d); om2 = __shfl_xor(m2B, d);
        take = (om1 < m1B) || (om1 == m1B && ok1 < k1B);
        nm2 = take ? fminf(m1B, om2) : fminf(m2B, om1);
        if (take) { m1B = om1; k1B = ok1; }
        m2B = nm2;
    }

    if (lane < 16) {
        int na  = n0 + (2 * w + 0) * 16 + lane;
        int nb_ = n0 + (2 * w + 1) * 16 + lane;
        bestk[na]  = k1A;
        bestk[nb_] = k1B;
        if (m2A - m1A <= DELTA) { int p = atomicAdd(cnt, 1); list[p] = na; }
        if (m2B - m1B <= DELTA) { int p = atomicAdd(cnt, 1); list[p] = nb_; }
    }
}

// ---------- rescue (R19 verbatim): wave-parallel exact f32 rescan ----------
__global__ __launch_bounds__(256) void vq_rescue(const float* __restrict__ z_e,
                                                 const float* __restrict__ emb,
                                                 const float* __restrict__ E,
                                                 const int* __restrict__ list,
                                                 const int* __restrict__ cnt,
                                                 int* __restrict__ bestk) {
    const int total  = cnt[0];
    const int lane   = threadIdx.x & 63;
    const int wid    = (blockIdx.x * 256 + threadIdx.x) >> 6;
    const int nwaves = (gridDim.x * 256) >> 6;

    for (int i = wid; i < total; i += nwaves) {
        const int n  = list[i];
        const int b  = n >> 12, wh = n & 4095;
        const float* zp = z_e + (size_t)b * CWH + wh;
        float z[CDIM];
#pragma unroll
        for (int c = 0; c < CDIM; ++c) z[c] = zp[c * WH];

        float best = 1e30f; int bk = 0;
        const int kbase = lane * 16;
#pragma unroll 4
        for (int j = 0; j < 16; ++j) {
            const int k = kbase + j;
            const float4* er4 = (const float4*)(emb + k * CDIM);
            float d0 = 0.f, d1 = 0.f, d2 = 0.f, d3 = 0.f;
#pragma unroll
            for (int c4 = 0; c4 < CDIM / 4; ++c4) {
                float4 v = er4[c4];
                d0 = fmaf(z[4 * c4 + 0], v.x, d0);
                d1 = fmaf(z[4 * c4 + 1], v.y, d1);
                d2 = fmaf(z[4 * c4 + 2], v.z, d2);
                d3 = fmaf(z[4 * c4 + 3], v.w, d3);
            }
            float dot   = (d0 + d1) + (d2 + d3);
            float score = fmaf(-2.0f, dot, E[k]);
            if (score < best) { best = score; bk = k; }
        }
#pragma unroll
        for (int d = 1; d < 64; d <<= 1) {
            float ob = __shfl_xor(best, d);
            int   ok = __shfl_xor(bk, d);
            if (ob < best || (ob == best && ok < bk)) { best = ob; bk = ok; }
        }
        if (lane == 0) bestk[n] = bk;
    }
}

// ---------- merge (R19 verbatim): vector emb gathers + register transpose ----------
__global__ __launch_bounds__(256) void vq_merge(const float* __restrict__ z_e,
                                                const float* __restrict__ emb,
                                                const int* __restrict__ kf,
                                                float* __restrict__ out_q,
                                                float* __restrict__ out_idx,
                                                float* __restrict__ partials) {
    const int tid = threadIdx.x;
    const int cq  = tid >> 5;
    const int pq  = tid & 31;
    const int n0  = blockIdx.x * 128 + pq * 4;
    const int b   = n0 >> 12;
    const int wh  = n0 & 4095;

    const int4 mk4 = *(const int4*)&kf[n0];
    if (cq == 0) {
        float4 fx = { (float)mk4.x, (float)mk4.y, (float)mk4.z, (float)mk4.w };
        *(float4*)&out_idx[n0] = fx;
    }

    const int c0 = cq * 8;
    float4 e0a = *(const float4*)&emb[mk4.x * CDIM + c0];
    float4 e0b = *(const float4*)&emb[mk4.x * CDIM + c0 + 4];
    float4 e1a = *(const float4*)&emb[mk4.y * CDIM + c0];
    float4 e1b = *(const float4*)&emb[mk4.y * CDIM + c0 + 4];
    float4 e2a = *(const float4*)&emb[mk4.z * CDIM + c0];
    float4 e2b = *(const float4*)&emb[mk4.z * CDIM + c0 + 4];
    float4 e3a = *(const float4*)&emb[mk4.w * CDIM + c0];
    float4 e3b = *(const float4*)&emb[mk4.w * CDIM + c0 + 4];

    float qv[8][4];
    qv[0][0] = e0a.x; qv[0][1] = e1a.x; qv[0][2] = e2a.x; qv[0][3] = e3a.x;
    qv[1][0] = e0a.y; qv[1][1] = e1a.y; qv[1][2] = e2a.y; qv[1][3] = e3a.y;
    qv[2][0] = e0a.z; qv[2][1] = e1a.z; qv[2][2] = e2a.z; qv[2][3] = e3a.z;
    qv[3][0] = e0a.w; qv[3][1] = e1a.w; qv[3][2] = e2a.w; qv[3][3] = e3a.w;
    qv[4][0] = e0b.x; qv[4][1] = e1b.x; qv[4][2] = e2b.x; qv[4][3] = e3b.x;
    qv[5][0] = e0b.y; qv[5][1] = e1b.y; qv[5][2] = e2b.y; qv[5][3] = e3b.y;
    qv[6][0] = e0b.z; qv[6][1] = e1b.z; qv[6][2] = e2b.z; qv[6][3] = e3b.z;
    qv[7][0] = e0b.w; qv[7][1] = e1b.w; qv[7][2] = e2b.w; qv[7][3] = e3b.w;

    const float* zb = z_e   + (size_t)b * CWH + wh;
    float*       qb = out_q + (size_t)b * CWH + wh;
    float lsum = 0.f;
#pragma unroll
    for (int cc = 0; cc < 8; ++cc) {
        const int c = c0 + cc;
        float4 z4 = *(const float4*)&zb[(size_t)c * WH];
        float4 q4 = { qv[cc][0], qv[cc][1], qv[cc][2], qv[cc][3] };
        *(float4*)&qb[(size_t)c * WH] = q4;
        float dx = q4.x - z4.x, dy = q4.y - z4.y;
        float dz = q4.z - z4.z, dw = q4.w - z4.w;
        lsum = fmaf(dx, dx, lsum); lsum = fmaf(dy, dy, lsum);
        lsum = fmaf(dz, dz, lsum); lsum = fmaf(dw, dw, lsum);
    }

    __shared__ float red[256];
    red[tid] = lsum;
    __syncthreads();
    for (int s = 128; s > 0; s >>= 1) {
        if (tid < s) red[tid] += red[tid + s];
        __syncthreads();
    }
    if (tid == 0) partials[blockIdx.x] = red[0];
}

__global__ __launch_bounds__(1024) void vq_loss_fin(const float* __restrict__ partials,
                                                    float* __restrict__ loss) {
    __shared__ float red[1024];
    int t = threadIdx.x;
    red[t] = partials[t];
    __syncthreads();
    for (int s = 512; s > 0; s >>= 1) {
        if (t < s) red[t] += red[t + s];
        __syncthreads();
    }
    if (t == 0) loss[0] = red[0] * (1.25f / 8388608.0f);
}

extern "C" void kernel_launch(void* const* d_in, const int* in_sizes, int n_in,
                              void* d_out, int out_size, void* d_ws, size_t ws_size,
                              hipStream_t stream) {
    const float* z_e = (const float*)d_in[0];
    const float* emb = (const float*)d_in[1];

    float* out      = (float*)d_out;
    float* out_q    = out;
    float* out_idx  = out + 8388608;
    float* out_loss = out + 8388608 + 131072;

    char* w = (char*)d_ws;
    float*          E        = (float*)(w);                    //   4 KB
    unsigned short* e_swz    = (unsigned short*)(w + 4096);    // 256 KB
    int*            bestk    = (int*)(w + 266240);             // 512 KB
    int*            list     = (int*)(w + 790528);             // 512 KB
    int*            cnt      = (int*)(w + 1314816);            //   4 B
    float*          partials = (float*)(w + 1315840);          //   4 KB

    vq_prep<<<32, 256, 0, stream>>>(emb, e_swz, E, cnt);
    vq_scan_mfma<<<NPTS / 128, 256, 0, stream>>>(z_e, e_swz, E, bestk, list, cnt);
    vq_rescue<<<2048, 256, 0, stream>>>(z_e, emb, E, list, cnt, bestk);
    vq_merge<<<NPTS / 128, 256, 0, stream>>>(z_e, emb, bestk, out_q, out_idx, partials);
    vq_loss_fin<<<1, 1024, 0, stream>>>(partials, out_loss);
}